// Round 7
// baseline (5095.914 us; speedup 1.0000x reference)
//
#include <hip/hip_runtime.h>
#include <hip/hip_cooperative_groups.h>
#include <stdint.h>

typedef unsigned short u16;
typedef __bf16 bf16_t;
typedef bf16_t bf16x8 __attribute__((ext_vector_type(8)));
typedef float f32x4 __attribute__((ext_vector_type(4)));

#define Bdim 64
#define Tdim 256
#define Ddim 512
#define Hdim 1024
#define NGdim 4096

// ---------- helpers ----------
__device__ __forceinline__ u16 f2bf(float f) {
  union { float f; uint32_t u; } v; v.f = f;
  return (u16)((v.u + 0x7FFFu + ((v.u >> 16) & 1u)) >> 16);   // RNE
}
__device__ __forceinline__ float bf2f(u16 h) {
  union { uint32_t u; float f; } v; v.u = ((uint32_t)h) << 16;
  return v.f;
}
__device__ __forceinline__ float sigm(float x) { return 1.0f / (1.0f + __expf(-x)); }
__device__ __forceinline__ float tanh_fast(float x) { return 2.0f / (1.0f + __expf(-2.0f * x)) - 1.0f; }

__device__ __forceinline__ void load_lds16(const void* g, void* l) {
  __builtin_amdgcn_global_load_lds(
      (const __attribute__((address_space(1))) uint32_t*)g,
      (__attribute__((address_space(3))) uint32_t*)l, 16, 0, 0);
}
__device__ __forceinline__ f32x4 mfma_bf16(bf16x8 a, bf16x8 b, f32x4 c) {
  return __builtin_amdgcn_mfma_f32_16x16x32_bf16(a, b, c, 0, 0, 0);
}

// ---------- kernel 0: zero h double-buffer + barrier counters ----------
__global__ void k_init(uint64_t* __restrict__ zreg) {
  zreg[blockIdx.x * 256 + threadIdx.x] = 0ull;   // 129 WGs x 256 x 8 B = 264 KB
}

// ---------- kernel 1: x fp32 -> bf16 ----------
__global__ void k_convert_x(const float* __restrict__ x, u16* __restrict__ xb) {
  const int i = (blockIdx.x * 256 + threadIdx.x) * 4;
  float4 v = *(const float4*)(x + i);
  union { u16 h[4]; uint2 v2; } p;
  p.h[0] = f2bf(v.x); p.h[1] = f2bf(v.y); p.h[2] = f2bf(v.z); p.h[3] = f2bf(v.w);
  *(uint2*)(xb + i) = p.v2;
}

// ---------- kernel 2: W[0:512][4096] fp32 -> WxT bf16 [4096][512] ----------
__global__ void k_transpose_wx(const float* __restrict__ W, u16* __restrict__ wxt) {
  __shared__ float tile[64][65];
  const int k0 = blockIdx.x * 64;   // 8 blocks
  const int n0 = blockIdx.y * 64;   // 64 blocks
  const int tn = threadIdx.x & 63, tk = threadIdx.x >> 6;
#pragma unroll
  for (int r = 0; r < 16; r++) {
    const int k = r * 4 + tk;
    tile[k][tn] = W[(size_t)(k0 + k) * NGdim + n0 + tn];
  }
  __syncthreads();
  for (int cid = threadIdx.x; cid < 512; cid += 256) {
    const int nl = cid >> 3, kc = cid & 7;
    union { u16 h[8]; uint4 v; } p;
#pragma unroll
    for (int j = 0; j < 8; j++) p.h[j] = f2bf(tile[kc * 8 + j][nl]);
    *(uint4*)(wxt + (size_t)(n0 + nl) * Ddim + k0 + kc * 8) = p.v;
  }
}

// ---------- kernel 3: XW = x @ Wx + b, permuted output [T][256 g][64 b][16 nl] bf16 ----------
__global__ __launch_bounds__(256) void k_gemm_xw(
    const u16* __restrict__ xb, const u16* __restrict__ wxt,
    const float* __restrict__ bias, u16* __restrict__ xw)
{
  __shared__ u16 smem[8192];        // 16 KB: sA [kg][128 m][8], sB [kg][128 j][8]
  const int Mtile = blockIdx.x;     // 0..127 (2 t's x 64 b)
  const int Ntile = blockIdx.y;     // 0..31
  const int g0 = Ntile * 8;
  const int tid = threadIdx.x;
  const int lane = tid & 63;
  const int wave = tid >> 6;
  const int wm = wave & 1, wn = wave >> 1;
  const int t0 = Mtile * 2;

  const size_t a_r0 = ((size_t)lane * Tdim + t0) * Ddim;
  const size_t a_r1 = ((size_t)lane * Tdim + t0 + 1) * Ddim;
  const int jc0 = lane, jc1 = 64 + lane;
  const int ng0 = (jc0 >> 5) * 1024 + (g0 + ((jc0 >> 2) & 7)) * 4 + (jc0 & 3);
  const int ng1 = (jc1 >> 5) * 1024 + (g0 + ((jc1 >> 2) & 7)) * 4 + (jc1 & 3);
  const size_t b_r0 = (size_t)ng0 * Ddim;
  const size_t b_r1 = (size_t)ng1 * Ddim;

  u16* sA = smem;
  u16* sB = smem + 4096;
  char* dA0 = (char*)sA + wave * 2048;
  char* dA1 = dA0 + 1024;
  char* dB0 = (char*)sB + wave * 2048;
  char* dB1 = dB0 + 1024;

  f32x4 zero4 = {0.f, 0.f, 0.f, 0.f};
  f32x4 acc[4][4];
#pragma unroll
  for (int i = 0; i < 4; i++)
#pragma unroll
    for (int j = 0; j < 4; j++) acc[i][j] = zero4;

  const int fa = (((lane >> 4) * 128) + wm * 64 + (lane & 15)) * 16;
  const int fb = (((lane >> 4) * 128) + wn * 64 + (lane & 15)) * 16;

  for (int k0 = 0; k0 < Ddim; k0 += 32) {
    const int koff = k0 + 8 * wave;
    __syncthreads();
    load_lds16(xb + a_r0 + koff, dA0);
    load_lds16(xb + a_r1 + koff, dA1);
    load_lds16(wxt + b_r0 + koff, dB0);
    load_lds16(wxt + b_r1 + koff, dB1);
    __syncthreads();
    bf16x8 af[4], bfr[4];
#pragma unroll
    for (int i = 0; i < 4; i++) {
      af[i]  = *(const bf16x8*)((const char*)sA + fa + i * 256);
      bfr[i] = *(const bf16x8*)((const char*)sB + fb + i * 256);
    }
#pragma unroll
    for (int mt = 0; mt < 4; mt++)
#pragma unroll
      for (int nt = 0; nt < 4; nt++)
        acc[mt][nt] = mfma_bf16(af[mt], bfr[nt], acc[mt][nt]);
  }

#pragma unroll 1
  for (int th = 0; th < 2; th++) {
    __syncthreads();
    if (wm == th) {
      const int q = lane >> 4, col0 = wn * 64 + (lane & 15);
#pragma unroll
      for (int mt = 0; mt < 4; mt++)
#pragma unroll
        for (int nt = 0; nt < 4; nt++)
#pragma unroll
          for (int i = 0; i < 4; i++)
            smem[(mt * 16 + q * 4 + i) * 128 + col0 + nt * 16] = f2bf(acc[mt][nt][i]);
    }
    __syncthreads();
    const int t = t0 + th;
    for (int cid = tid; cid < 512; cid += 256) {
      const int gsub = cid >> 6;
      const int b = cid & 63;
      union { u16 h[16]; uint4 v[2]; } pack;
#pragma unroll
      for (int gate = 0; gate < 4; gate++)
#pragma unroll
        for (int c = 0; c < 4; c++) {
          float v = bf2f(smem[b * 128 + gate * 32 + gsub * 4 + c])
                  + bias[gate * 1024 + (g0 + gsub) * 4 + c];
          pack.h[gate * 4 + c] = f2bf(v);
        }
      uint4* dst = (uint4*)(xw + ((((size_t)t * 256) + g0 + gsub) * 64 + b) * 16);
      dst[0] = pack.v[0];
      dst[1] = pack.v[1];
    }
  }
}

// ---------- kernel 4: persistent LSTM, phase-flag agent barrier ----------
// 256 WGs x 256 thr, 1 WG/CU. WG gid owns h-cols [gid*4, gid*4+4) x 4 gates.
// Barrier protocol (per step):
//   __syncthreads (drains ALL waves' h stores into L2)
//   tid0: fence(RELEASE, agent)            -> one buffer_wbl2 per WG (h -> MALL)
//   tid0: fetch_add(gctr, 1, RELAXED, agent)   (RMW executes at coherence point)
//   last arriver: fence(ACQUIRE) + atomic_store(phase, t+1, RELEASE, agent)
//   tid0: spin on atomic_load(phase, ACQUIRE, agent)  (correct sc bits + buffer_inv)
//   __syncthreads
// Anti-wedge: bounded spin -> broken barrier gives fast wrong answer, not a hang.
__global__ __launch_bounds__(256, 1) void k_lstm(
    const float* __restrict__ W, const u16* __restrict__ xw,
    const int* __restrict__ seq_len, u16* __restrict__ hbuf,
    uint32_t* __restrict__ bar, float* __restrict__ out)
{
  __shared__ u16 wlds[128 * 16 * 8];   // 32 KB, one-time W_h staging
  __shared__ float zlds[64 * 17];      // padded z tile
  const int gid = blockIdx.x;          // 0..255
  const int tid = threadIdx.x;
  const int lane = tid & 63;
  const int wave = tid >> 6;           // batch rows wave*16..wave*16+15

  { // one-time W_h slice load -> LDS bf16 (verified round-1 mapping)
    const int gate = tid & 3;
    const int kb = tid >> 2;           // 0..63
    const int ngc = gate * 1024 + gid * 4;
#pragma unroll 1
    for (int kk = 0; kk < 16; kk++) {
      const int k = kb * 16 + kk;
      const float4 wv = *(const float4*)(W + (size_t)(Ddim + k) * NGdim + ngc);
      const int base = ((k >> 3) * 16 + gate * 4) * 8 + (k & 7);
      wlds[base]      = f2bf(wv.x);
      wlds[base + 8]  = f2bf(wv.y);
      wlds[base + 16] = f2bf(wv.z);
      wlds[base + 24] = f2bf(wv.w);
    }
  }
  __syncthreads();

  // hoist B-fragments (W_h) into VGPRs: identical indexing to the per-step LDS read
  const int fbo = ((lane >> 4) * 16 + (lane & 15)) * 8;
  bf16x8 wreg[32];
#pragma unroll
  for (int kt = 0; kt < 32; kt++)
    wreg[kt] = *(const bf16x8*)(wlds + kt * 512 + fbo);

  const int b_t = tid >> 2, c_t = tid & 3;
  const int slen = seq_len[b_t];
  float c_reg = 0.f, h_reg = 0.f;

  const size_t a0 = ((size_t)(wave * 16 + (lane & 15)) * Hdim) + (lane >> 4) * 8;
  const int q = lane >> 4, col = lane & 15;
  const f32x4 zero4 = {0.f, 0.f, 0.f, 0.f};
  uint32_t* gctr  = bar;        // arrival counter
  uint32_t* phase = bar + 32;   // published step (separate cache line)

  for (int t = 0; t < Tdim; t++) {
    const u16* hsrc = hbuf + (size_t)(t & 1) * (Bdim * Hdim);
    u16* hdst = hbuf + (size_t)((t + 1) & 1) * (Bdim * Hdim);

    // xw for this step (plain cached loads; compiler-managed waits)
    const u16* xwp = xw + ((((size_t)t * 256) + gid) * 64 + b_t) * 16 + c_t;
    const u16 xwi = xwp[0], xwj = xwp[4], xwf = xwp[8], xwo = xwp[12];

    // h @ W_h partial (verified round-1/6 dataflow, plain loads)
    const u16* pA = hsrc + a0;
    f32x4 acc[4] = {zero4, zero4, zero4, zero4};
#pragma unroll
    for (int kt = 0; kt < 32; kt++)
      acc[kt & 3] = mfma_bf16(*(const bf16x8*)(pA + (size_t)kt * 32), wreg[kt], acc[kt & 3]);

    { // z tile -> LDS
      const int r0 = wave * 16 + q * 4;
#pragma unroll
      for (int i = 0; i < 4; i++)
        zlds[(r0 + i) * 17 + col] = acc[0][i] + acc[1][i] + acc[2][i] + acc[3][i];
    }
    __syncthreads();
    { // gates + state update: thread owns (batch b_t, h-col gid*4+c_t)
      float zi = zlds[b_t * 17 + 0  + c_t] + bf2f(xwi);
      float zj = zlds[b_t * 17 + 4  + c_t] + bf2f(xwj);
      float zf = zlds[b_t * 17 + 8  + c_t] + bf2f(xwf);
      float zo = zlds[b_t * 17 + 12 + c_t] + bf2f(xwo);
      if (t < slen) {
        c_reg = c_reg * sigm(zf + 1.0f) + sigm(zi) * tanh_fast(zj);
        h_reg = tanh_fast(c_reg) * sigm(zo);
      }
      hdst[(size_t)b_t * Hdim + gid * 4 + c_t] = f2bf(h_reg);   // plain store
    }

    if (t < Tdim - 1) {
      __syncthreads();           // every wave's h store drained into L2 (vmcnt0+barrier)
      if (tid == 0) {
        __builtin_amdgcn_fence(__ATOMIC_RELEASE, "agent");   // one wbl2: h -> MALL
        const uint32_t old = __hip_atomic_fetch_add(gctr, 1u, __ATOMIC_RELAXED,
                                                    __HIP_MEMORY_SCOPE_AGENT);
        const uint32_t tgt = (uint32_t)(t + 1);
        if (old == tgt * 256u - 1u) {            // last arriver publishes the phase
          __builtin_amdgcn_fence(__ATOMIC_ACQUIRE, "agent");
          __hip_atomic_store(phase, tgt, __ATOMIC_RELEASE, __HIP_MEMORY_SCOPE_AGENT);
        }
        uint32_t guard = 0;
        while (__hip_atomic_load(phase, __ATOMIC_ACQUIRE,
                                 __HIP_MEMORY_SCOPE_AGENT) < tgt) {
          if (++guard > 65536u) break;           // anti-wedge: fail fast, not hang
          __builtin_amdgcn_s_sleep(2);
        }
      }
      __syncthreads();           // WG proceeds; acquire-load's buffer_inv covered L1/L2
    }
  }
  out[(size_t)b_t * Hdim + gid * 4 + c_t] = h_reg;
}

// ---------- host ----------
extern "C" void kernel_launch(void* const* d_in, const int* in_sizes, int n_in,
                              void* d_out, int out_size, void* d_ws, size_t ws_size,
                              hipStream_t stream) {
  (void)in_sizes; (void)n_in; (void)out_size; (void)ws_size;
  const float* x       = (const float*)d_in[0];
  const int*   seq_len = (const int*)d_in[1];
  const float* W       = (const float*)d_in[2];
  const float* bias    = (const float*)d_in[3];
  float* out = (float*)d_out;

  char* ws = (char*)d_ws;
  u16*   xw   = (u16*)(ws);                                  // 128 MB [T][256][64][16] bf16
  u16*   xb   = (u16*)(ws + (size_t)134217728);              // 16 MB  x bf16 [B][T][D]
  u16*   wxt  = (u16*)(ws + (size_t)150994944);              // 4 MB   WxT bf16 [4096][512]
  char*  hreg = ws + (size_t)155189248;                      // 256 KB h dbuf + barrier line
  u16*   hbuf = (u16*)hreg;
  uint32_t* bar = (uint32_t*)(hreg + 262144);                // gctr @+0, phase @+128B

  k_init<<<dim3(129), dim3(256), 0, stream>>>((uint64_t*)hreg);   // zero h dbuf + bar
  k_convert_x<<<dim3(8192), dim3(256), 0, stream>>>(x, xb);
  k_transpose_wx<<<dim3(8, 64), dim3(256), 0, stream>>>(W, wxt);
  k_gemm_xw<<<dim3(128, 32), dim3(256), 0, stream>>>(xb, wxt, bias, xw);

  void* args[6];
  args[0] = (void*)&W;
  args[1] = (void*)&xw;
  args[2] = (void*)&seq_len;
  args[3] = (void*)&hbuf;
  args[4] = (void*)&bar;
  args[5] = (void*)&out;
  (void)hipLaunchCooperativeKernel((const void*)k_lstm, dim3(256), dim3(256), args, 0, stream);
}

// Round 8
// 3600.333 us; speedup vs baseline: 1.4154x; 1.4154x over previous
//
#include <hip/hip_runtime.h>
#include <hip/hip_cooperative_groups.h>
#include <stdint.h>

typedef unsigned short u16;
typedef __bf16 bf16_t;
typedef bf16_t bf16x8 __attribute__((ext_vector_type(8)));
typedef float f32x4 __attribute__((ext_vector_type(4)));

#define Bdim 64
#define Tdim 256
#define Ddim 512
#define Hdim 1024
#define NGdim 4096

// ---------- helpers ----------
__device__ __forceinline__ u16 f2bf(float f) {
  union { float f; uint32_t u; } v; v.f = f;
  return (u16)((v.u + 0x7FFFu + ((v.u >> 16) & 1u)) >> 16);   // RNE
}
__device__ __forceinline__ float bf2f(u16 h) {
  union { uint32_t u; float f; } v; v.u = ((uint32_t)h) << 16;
  return v.f;
}
__device__ __forceinline__ float sigm(float x) { return 1.0f / (1.0f + __expf(-x)); }
__device__ __forceinline__ float tanh_fast(float x) { return 2.0f / (1.0f + __expf(-2.0f * x)) - 1.0f; }

__device__ __forceinline__ void load_lds16(const void* g, void* l) {
  __builtin_amdgcn_global_load_lds(
      (const __attribute__((address_space(1))) uint32_t*)g,
      (__attribute__((address_space(3))) uint32_t*)l, 16, 0, 0);
}
__device__ __forceinline__ f32x4 mfma_bf16(bf16x8 a, bf16x8 b, f32x4 c) {
  return __builtin_amdgcn_mfma_f32_16x16x32_bf16(a, b, c, 0, 0, 0);
}

// ---------- kernel 0: zero h double-buffer + barrier counters ----------
__global__ void k_init(uint64_t* __restrict__ zreg) {
  zreg[blockIdx.x * 256 + threadIdx.x] = 0ull;   // 129 WGs x 256 x 8 B = 264 KB
}

// ---------- kernel 1: x fp32 -> bf16 ----------
__global__ void k_convert_x(const float* __restrict__ x, u16* __restrict__ xb) {
  const int i = (blockIdx.x * 256 + threadIdx.x) * 4;
  float4 v = *(const float4*)(x + i);
  union { u16 h[4]; uint2 v2; } p;
  p.h[0] = f2bf(v.x); p.h[1] = f2bf(v.y); p.h[2] = f2bf(v.z); p.h[3] = f2bf(v.w);
  *(uint2*)(xb + i) = p.v2;
}

// ---------- kernel 2: W[0:512][4096] fp32 -> WxT bf16 [4096][512] ----------
__global__ void k_transpose_wx(const float* __restrict__ W, u16* __restrict__ wxt) {
  __shared__ float tile[64][65];
  const int k0 = blockIdx.x * 64;   // 8 blocks
  const int n0 = blockIdx.y * 64;   // 64 blocks
  const int tn = threadIdx.x & 63, tk = threadIdx.x >> 6;
#pragma unroll
  for (int r = 0; r < 16; r++) {
    const int k = r * 4 + tk;
    tile[k][tn] = W[(size_t)(k0 + k) * NGdim + n0 + tn];
  }
  __syncthreads();
  for (int cid = threadIdx.x; cid < 512; cid += 256) {
    const int nl = cid >> 3, kc = cid & 7;
    union { u16 h[8]; uint4 v; } p;
#pragma unroll
    for (int j = 0; j < 8; j++) p.h[j] = f2bf(tile[kc * 8 + j][nl]);
    *(uint4*)(wxt + (size_t)(n0 + nl) * Ddim + k0 + kc * 8) = p.v;
  }
}

// ---------- kernel 3: XW = x @ Wx + b, permuted output [T][256 g][64 b][16 nl] bf16 ----------
__global__ __launch_bounds__(256) void k_gemm_xw(
    const u16* __restrict__ xb, const u16* __restrict__ wxt,
    const float* __restrict__ bias, u16* __restrict__ xw)
{
  __shared__ u16 smem[8192];        // 16 KB: sA [kg][128 m][8], sB [kg][128 j][8]
  const int Mtile = blockIdx.x;     // 0..127 (2 t's x 64 b)
  const int Ntile = blockIdx.y;     // 0..31
  const int g0 = Ntile * 8;
  const int tid = threadIdx.x;
  const int lane = tid & 63;
  const int wave = tid >> 6;
  const int wm = wave & 1, wn = wave >> 1;
  const int t0 = Mtile * 2;

  const size_t a_r0 = ((size_t)lane * Tdim + t0) * Ddim;
  const size_t a_r1 = ((size_t)lane * Tdim + t0 + 1) * Ddim;
  const int jc0 = lane, jc1 = 64 + lane;
  const int ng0 = (jc0 >> 5) * 1024 + (g0 + ((jc0 >> 2) & 7)) * 4 + (jc0 & 3);
  const int ng1 = (jc1 >> 5) * 1024 + (g0 + ((jc1 >> 2) & 7)) * 4 + (jc1 & 3);
  const size_t b_r0 = (size_t)ng0 * Ddim;
  const size_t b_r1 = (size_t)ng1 * Ddim;

  u16* sA = smem;
  u16* sB = smem + 4096;
  char* dA0 = (char*)sA + wave * 2048;
  char* dA1 = dA0 + 1024;
  char* dB0 = (char*)sB + wave * 2048;
  char* dB1 = dB0 + 1024;

  f32x4 zero4 = {0.f, 0.f, 0.f, 0.f};
  f32x4 acc[4][4];
#pragma unroll
  for (int i = 0; i < 4; i++)
#pragma unroll
    for (int j = 0; j < 4; j++) acc[i][j] = zero4;

  const int fa = (((lane >> 4) * 128) + wm * 64 + (lane & 15)) * 16;
  const int fb = (((lane >> 4) * 128) + wn * 64 + (lane & 15)) * 16;

  for (int k0 = 0; k0 < Ddim; k0 += 32) {
    const int koff = k0 + 8 * wave;
    __syncthreads();
    load_lds16(xb + a_r0 + koff, dA0);
    load_lds16(xb + a_r1 + koff, dA1);
    load_lds16(wxt + b_r0 + koff, dB0);
    load_lds16(wxt + b_r1 + koff, dB1);
    __syncthreads();
    bf16x8 af[4], bfr[4];
#pragma unroll
    for (int i = 0; i < 4; i++) {
      af[i]  = *(const bf16x8*)((const char*)sA + fa + i * 256);
      bfr[i] = *(const bf16x8*)((const char*)sB + fb + i * 256);
    }
#pragma unroll
    for (int mt = 0; mt < 4; mt++)
#pragma unroll
      for (int nt = 0; nt < 4; nt++)
        acc[mt][nt] = mfma_bf16(af[mt], bfr[nt], acc[mt][nt]);
  }

#pragma unroll 1
  for (int th = 0; th < 2; th++) {
    __syncthreads();
    if (wm == th) {
      const int q = lane >> 4, col0 = wn * 64 + (lane & 15);
#pragma unroll
      for (int mt = 0; mt < 4; mt++)
#pragma unroll
        for (int nt = 0; nt < 4; nt++)
#pragma unroll
          for (int i = 0; i < 4; i++)
            smem[(mt * 16 + q * 4 + i) * 128 + col0 + nt * 16] = f2bf(acc[mt][nt][i]);
    }
    __syncthreads();
    const int t = t0 + th;
    for (int cid = tid; cid < 512; cid += 256) {
      const int gsub = cid >> 6;
      const int b = cid & 63;
      union { u16 h[16]; uint4 v[2]; } pack;
#pragma unroll
      for (int gate = 0; gate < 4; gate++)
#pragma unroll
        for (int c = 0; c < 4; c++) {
          float v = bf2f(smem[b * 128 + gate * 32 + gsub * 4 + c])
                  + bias[gate * 1024 + (g0 + gsub) * 4 + c];
          pack.h[gate * 4 + c] = f2bf(v);
        }
      uint4* dst = (uint4*)(xw + ((((size_t)t * 256) + g0 + gsub) * 64 + b) * 16);
      dst[0] = pack.v[0];
      dst[1] = pack.v[1];
    }
  }
}

// ---------- kernel 4: persistent LSTM, phase-flag agent barrier (v2) ----------
// vs round 7 (verified): RELAXED spin polls (no buffer_inv per poll) + single
// ACQUIRE fence after spin exit; RELAXED phase publish; xw[t+1] register-prefetch
// issued before the barrier (registers survive the acquire invalidation).
__global__ __launch_bounds__(256, 1) void k_lstm(
    const float* __restrict__ W, const u16* __restrict__ xw,
    const int* __restrict__ seq_len, u16* __restrict__ hbuf,
    uint32_t* __restrict__ bar, float* __restrict__ out)
{
  __shared__ u16 wlds[128 * 16 * 8];   // 32 KB, one-time W_h staging
  __shared__ float zlds[64 * 17];      // padded z tile
  const int gid = blockIdx.x;          // 0..255
  const int tid = threadIdx.x;
  const int lane = tid & 63;
  const int wave = tid >> 6;           // batch rows wave*16..wave*16+15

  { // one-time W_h slice load -> LDS bf16 (verified round-1 mapping)
    const int gate = tid & 3;
    const int kb = tid >> 2;           // 0..63
    const int ngc = gate * 1024 + gid * 4;
#pragma unroll 1
    for (int kk = 0; kk < 16; kk++) {
      const int k = kb * 16 + kk;
      const float4 wv = *(const float4*)(W + (size_t)(Ddim + k) * NGdim + ngc);
      const int base = ((k >> 3) * 16 + gate * 4) * 8 + (k & 7);
      wlds[base]      = f2bf(wv.x);
      wlds[base + 8]  = f2bf(wv.y);
      wlds[base + 16] = f2bf(wv.z);
      wlds[base + 24] = f2bf(wv.w);
    }
  }
  __syncthreads();

  // hoist B-fragments (W_h) into VGPRs
  const int fbo = ((lane >> 4) * 16 + (lane & 15)) * 8;
  bf16x8 wreg[32];
#pragma unroll
  for (int kt = 0; kt < 32; kt++)
    wreg[kt] = *(const bf16x8*)(wlds + kt * 512 + fbo);

  const int b_t = tid >> 2, c_t = tid & 3;
  const int slen = seq_len[b_t];
  float c_reg = 0.f, h_reg = 0.f;

  const size_t a0 = ((size_t)(wave * 16 + (lane & 15)) * Hdim) + (lane >> 4) * 8;
  const int q = lane >> 4, col = lane & 15;
  const f32x4 zero4 = {0.f, 0.f, 0.f, 0.f};
  uint32_t* gctr  = bar;        // arrival counter (MALL-resident)
  uint32_t* phase = bar + 32;   // published step (separate cache line)

  // xw register prefetch for t=0
  const u16* xwp0 = xw + ((size_t)gid * 64 + b_t) * 16 + c_t;
  u16 xwi = xwp0[0], xwj = xwp0[4], xwf = xwp0[8], xwo = xwp0[12];

  for (int t = 0; t < Tdim; t++) {
    const u16* hsrc = hbuf + (size_t)(t & 1) * (Bdim * Hdim);
    u16* hdst = hbuf + (size_t)((t + 1) & 1) * (Bdim * Hdim);

    // h @ W_h partial (verified dataflow, plain loads)
    const u16* pA = hsrc + a0;
    f32x4 acc[4] = {zero4, zero4, zero4, zero4};
#pragma unroll
    for (int kt = 0; kt < 32; kt++)
      acc[kt & 3] = mfma_bf16(*(const bf16x8*)(pA + (size_t)kt * 32), wreg[kt], acc[kt & 3]);

    { // z tile -> LDS
      const int r0 = wave * 16 + q * 4;
#pragma unroll
      for (int i = 0; i < 4; i++)
        zlds[(r0 + i) * 17 + col] = acc[0][i] + acc[1][i] + acc[2][i] + acc[3][i];
    }
    __syncthreads();
    { // gates + state update: thread owns (batch b_t, h-col gid*4+c_t)
      float zi = zlds[b_t * 17 + 0  + c_t] + bf2f(xwi);
      float zj = zlds[b_t * 17 + 4  + c_t] + bf2f(xwj);
      float zf = zlds[b_t * 17 + 8  + c_t] + bf2f(xwf);
      float zo = zlds[b_t * 17 + 12 + c_t] + bf2f(xwo);
      if (t < slen) {
        c_reg = c_reg * sigm(zf + 1.0f) + sigm(zi) * tanh_fast(zj);
        h_reg = tanh_fast(c_reg) * sigm(zo);
      }
      hdst[(size_t)b_t * Hdim + gid * 4 + c_t] = f2bf(h_reg);   // plain store
    }

    // register-prefetch next step's xw (issued before the barrier; values live in
    // registers, so the post-barrier acquire invalidation cannot touch them)
    if (t < Tdim - 1) {
      const u16* nx = xw + ((((size_t)(t + 1)) * 256 + gid) * 64 + b_t) * 16 + c_t;
      const u16 n_i = nx[0], n_j = nx[4], n_f = nx[8], n_o = nx[12];

      __syncthreads();           // every wave's h store drained into L2
      if (tid == 0) {
        __builtin_amdgcn_fence(__ATOMIC_RELEASE, "agent");   // one wbl2: h -> MALL
        const uint32_t old = __hip_atomic_fetch_add(gctr, 1u, __ATOMIC_RELAXED,
                                                    __HIP_MEMORY_SCOPE_AGENT);
        const uint32_t tgt = (uint32_t)(t + 1);
        if (old == tgt * 256u - 1u)              // last arriver publishes the phase
          __hip_atomic_store(phase, tgt, __ATOMIC_RELAXED, __HIP_MEMORY_SCOPE_AGENT);
        uint32_t guard = 0;
        while (__hip_atomic_load(phase, __ATOMIC_RELAXED,
                                 __HIP_MEMORY_SCOPE_AGENT) < tgt) {
          if (++guard > 65536u) break;           // anti-wedge: fail fast, not hang
          __builtin_amdgcn_s_sleep(2);
        }
        // single acquire per WG per step: inv L1(+L2) once, not per poll
        __builtin_amdgcn_fence(__ATOMIC_ACQUIRE, "agent");
      }
      __syncthreads();           // WG proceeds; h loads stay below (compiler+HW barrier)

      xwi = n_i; xwj = n_j; xwf = n_f; xwo = n_o;
    }
  }
  out[(size_t)b_t * Hdim + gid * 4 + c_t] = h_reg;
}

// ---------- host ----------
extern "C" void kernel_launch(void* const* d_in, const int* in_sizes, int n_in,
                              void* d_out, int out_size, void* d_ws, size_t ws_size,
                              hipStream_t stream) {
  (void)in_sizes; (void)n_in; (void)out_size; (void)ws_size;
  const float* x       = (const float*)d_in[0];
  const int*   seq_len = (const int*)d_in[1];
  const float* W       = (const float*)d_in[2];
  const float* bias    = (const float*)d_in[3];
  float* out = (float*)d_out;

  char* ws = (char*)d_ws;
  u16*   xw   = (u16*)(ws);                                  // 128 MB [T][256][64][16] bf16
  u16*   xb   = (u16*)(ws + (size_t)134217728);              // 16 MB  x bf16 [B][T][D]
  u16*   wxt  = (u16*)(ws + (size_t)150994944);              // 4 MB   WxT bf16 [4096][512]
  char*  hreg = ws + (size_t)155189248;                      // 256 KB h dbuf + barrier line
  u16*   hbuf = (u16*)hreg;
  uint32_t* bar = (uint32_t*)(hreg + 262144);                // gctr @+0, phase @+128B

  k_init<<<dim3(129), dim3(256), 0, stream>>>((uint64_t*)hreg);   // zero h dbuf + bar
  k_convert_x<<<dim3(8192), dim3(256), 0, stream>>>(x, xb);
  k_transpose_wx<<<dim3(8, 64), dim3(256), 0, stream>>>(W, wxt);
  k_gemm_xw<<<dim3(128, 32), dim3(256), 0, stream>>>(xb, wxt, bias, xw);

  void* args[6];
  args[0] = (void*)&W;
  args[1] = (void*)&xw;
  args[2] = (void*)&seq_len;
  args[3] = (void*)&hbuf;
  args[4] = (void*)&bar;
  args[5] = (void*)&out;
  (void)hipLaunchCooperativeKernel((const void*)k_lstm, dim3(256), dim3(256), args, 0, stream);
}

// Round 9
// 2753.104 us; speedup vs baseline: 1.8510x; 1.3077x over previous
//
#include <hip/hip_runtime.h>
#include <hip/hip_cooperative_groups.h>
#include <stdint.h>

typedef unsigned short u16;
typedef unsigned long long u64;
typedef __bf16 bf16_t;
typedef bf16_t bf16x8 __attribute__((ext_vector_type(8)));
typedef float f32x4 __attribute__((ext_vector_type(4)));

#define Bdim 64
#define Tdim 256
#define Ddim 512
#define Hdim 1024
#define NGdim 4096

// ---------- helpers ----------
__device__ __forceinline__ u16 f2bf(float f) {
  union { float f; uint32_t u; } v; v.f = f;
  return (u16)((v.u + 0x7FFFu + ((v.u >> 16) & 1u)) >> 16);   // RNE
}
__device__ __forceinline__ float bf2f(u16 h) {
  union { uint32_t u; float f; } v; v.u = ((uint32_t)h) << 16;
  return v.f;
}
__device__ __forceinline__ float sigm(float x) { return 1.0f / (1.0f + __expf(-x)); }
__device__ __forceinline__ float tanh_fast(float x) { return 2.0f / (1.0f + __expf(-2.0f * x)) - 1.0f; }

__device__ __forceinline__ void load_lds16(const void* g, void* l) {
  __builtin_amdgcn_global_load_lds(
      (const __attribute__((address_space(1))) uint32_t*)g,
      (__attribute__((address_space(3))) uint32_t*)l, 16, 0, 0);
}
__device__ __forceinline__ f32x4 mfma_bf16(bf16x8 a, bf16x8 b, f32x4 c) {
  return __builtin_amdgcn_mfma_f32_16x16x32_bf16(a, b, c, 0, 0, 0);
}

// ---------- kernel 0: zero h double-buffer + barrier counters ----------
__global__ void k_init(u64* __restrict__ zreg) {
  zreg[blockIdx.x * 256 + threadIdx.x] = 0ull;   // 129 WGs x 256 x 8 B = 264 KB
}

// ---------- kernel 1: x fp32 -> bf16 ----------
__global__ void k_convert_x(const float* __restrict__ x, u16* __restrict__ xb) {
  const int i = (blockIdx.x * 256 + threadIdx.x) * 4;
  float4 v = *(const float4*)(x + i);
  union { u16 h[4]; uint2 v2; } p;
  p.h[0] = f2bf(v.x); p.h[1] = f2bf(v.y); p.h[2] = f2bf(v.z); p.h[3] = f2bf(v.w);
  *(uint2*)(xb + i) = p.v2;
}

// ---------- kernel 2: W[0:512][4096] fp32 -> WxT bf16 [4096][512] ----------
__global__ void k_transpose_wx(const float* __restrict__ W, u16* __restrict__ wxt) {
  __shared__ float tile[64][65];
  const int k0 = blockIdx.x * 64;   // 8 blocks
  const int n0 = blockIdx.y * 64;   // 64 blocks
  const int tn = threadIdx.x & 63, tk = threadIdx.x >> 6;
#pragma unroll
  for (int r = 0; r < 16; r++) {
    const int k = r * 4 + tk;
    tile[k][tn] = W[(size_t)(k0 + k) * NGdim + n0 + tn];
  }
  __syncthreads();
  for (int cid = threadIdx.x; cid < 512; cid += 256) {
    const int nl = cid >> 3, kc = cid & 7;
    union { u16 h[8]; uint4 v; } p;
#pragma unroll
    for (int j = 0; j < 8; j++) p.h[j] = f2bf(tile[kc * 8 + j][nl]);
    *(uint4*)(wxt + (size_t)(n0 + nl) * Ddim + k0 + kc * 8) = p.v;
  }
}

// ---------- kernel 3: XW = x @ Wx + b, permuted output [T][256 g][64 b][16 nl] bf16 ----------
__global__ __launch_bounds__(256) void k_gemm_xw(
    const u16* __restrict__ xb, const u16* __restrict__ wxt,
    const float* __restrict__ bias, u16* __restrict__ xw)
{
  __shared__ u16 smem[8192];        // 16 KB: sA [kg][128 m][8], sB [kg][128 j][8]
  const int Mtile = blockIdx.x;     // 0..127 (2 t's x 64 b)
  const int Ntile = blockIdx.y;     // 0..31
  const int g0 = Ntile * 8;
  const int tid = threadIdx.x;
  const int lane = tid & 63;
  const int wave = tid >> 6;
  const int wm = wave & 1, wn = wave >> 1;
  const int t0 = Mtile * 2;

  const size_t a_r0 = ((size_t)lane * Tdim + t0) * Ddim;
  const size_t a_r1 = ((size_t)lane * Tdim + t0 + 1) * Ddim;
  const int jc0 = lane, jc1 = 64 + lane;
  const int ng0 = (jc0 >> 5) * 1024 + (g0 + ((jc0 >> 2) & 7)) * 4 + (jc0 & 3);
  const int ng1 = (jc1 >> 5) * 1024 + (g0 + ((jc1 >> 2) & 7)) * 4 + (jc1 & 3);
  const size_t b_r0 = (size_t)ng0 * Ddim;
  const size_t b_r1 = (size_t)ng1 * Ddim;

  u16* sA = smem;
  u16* sB = smem + 4096;
  char* dA0 = (char*)sA + wave * 2048;
  char* dA1 = dA0 + 1024;
  char* dB0 = (char*)sB + wave * 2048;
  char* dB1 = dB0 + 1024;

  f32x4 zero4 = {0.f, 0.f, 0.f, 0.f};
  f32x4 acc[4][4];
#pragma unroll
  for (int i = 0; i < 4; i++)
#pragma unroll
    for (int j = 0; j < 4; j++) acc[i][j] = zero4;

  const int fa = (((lane >> 4) * 128) + wm * 64 + (lane & 15)) * 16;
  const int fb = (((lane >> 4) * 128) + wn * 64 + (lane & 15)) * 16;

  for (int k0 = 0; k0 < Ddim; k0 += 32) {
    const int koff = k0 + 8 * wave;
    __syncthreads();
    load_lds16(xb + a_r0 + koff, dA0);
    load_lds16(xb + a_r1 + koff, dA1);
    load_lds16(wxt + b_r0 + koff, dB0);
    load_lds16(wxt + b_r1 + koff, dB1);
    __syncthreads();
    bf16x8 af[4], bfr[4];
#pragma unroll
    for (int i = 0; i < 4; i++) {
      af[i]  = *(const bf16x8*)((const char*)sA + fa + i * 256);
      bfr[i] = *(const bf16x8*)((const char*)sB + fb + i * 256);
    }
#pragma unroll
    for (int mt = 0; mt < 4; mt++)
#pragma unroll
      for (int nt = 0; nt < 4; nt++)
        acc[mt][nt] = mfma_bf16(af[mt], bfr[nt], acc[mt][nt]);
  }

#pragma unroll 1
  for (int th = 0; th < 2; th++) {
    __syncthreads();
    if (wm == th) {
      const int q = lane >> 4, col0 = wn * 64 + (lane & 15);
#pragma unroll
      for (int mt = 0; mt < 4; mt++)
#pragma unroll
        for (int nt = 0; nt < 4; nt++)
#pragma unroll
          for (int i = 0; i < 4; i++)
            smem[(mt * 16 + q * 4 + i) * 128 + col0 + nt * 16] = f2bf(acc[mt][nt][i]);
    }
    __syncthreads();
    const int t = t0 + th;
    for (int cid = tid; cid < 512; cid += 256) {
      const int gsub = cid >> 6;
      const int b = cid & 63;
      union { u16 h[16]; uint4 v[2]; } pack;
#pragma unroll
      for (int gate = 0; gate < 4; gate++)
#pragma unroll
        for (int c = 0; c < 4; c++) {
          float v = bf2f(smem[b * 128 + gate * 32 + gsub * 4 + c])
                  + bias[gate * 1024 + (g0 + gsub) * 4 + c];
          pack.h[gate * 4 + c] = f2bf(v);
        }
      uint4* dst = (uint4*)(xw + ((((size_t)t * 256) + g0 + gsub) * 64 + b) * 16);
      dst[0] = pack.v[0];
      dst[1] = pack.v[1];
    }
  }
}

// ---------- kernel 4: persistent LSTM, fence-free MALL-atomic exchange ----------
// 256 WGs x 256 thr, 1 WG/CU. WG gid owns h-cols [gid*4, gid*4+4) x 4 gates.
// h exchanged entirely via agent-scope RELAXED atomics (verified cross-XCD coherent
// in rounds 7/8's spin): 8B atomic stores write through to MALL; 8B atomic loads
// bypass stale L1/L2. ZERO fences / wbl2 / inv in the loop. Barrier = two-level
// spread counters + relaxed phase publish + relaxed spin.
__global__ __launch_bounds__(256, 1) void k_lstm(
    const float* __restrict__ W, const u16* __restrict__ xw,
    const int* __restrict__ seq_len, u16* __restrict__ hbuf,
    uint32_t* __restrict__ bar, float* __restrict__ out)
{
  __shared__ u16 wlds[128 * 16 * 8];   // 32 KB, one-time W_h staging
  __shared__ float zlds[64 * 17];      // padded z tile
  __shared__ u16 hlds[256];            // h gather for 8B packed stores
  const int gid = blockIdx.x;          // 0..255
  const int tid = threadIdx.x;
  const int lane = tid & 63;
  const int wave = tid >> 6;           // batch rows wave*16..wave*16+15

  { // one-time W_h slice load -> LDS bf16 (verified round-1 mapping)
    const int gate = tid & 3;
    const int kb = tid >> 2;           // 0..63
    const int ngc = gate * 1024 + gid * 4;
#pragma unroll 1
    for (int kk = 0; kk < 16; kk++) {
      const int k = kb * 16 + kk;
      const float4 wv = *(const float4*)(W + (size_t)(Ddim + k) * NGdim + ngc);
      const int base = ((k >> 3) * 16 + gate * 4) * 8 + (k & 7);
      wlds[base]      = f2bf(wv.x);
      wlds[base + 8]  = f2bf(wv.y);
      wlds[base + 16] = f2bf(wv.z);
      wlds[base + 24] = f2bf(wv.w);
    }
  }
  __syncthreads();

  // hoist B-fragments (W_h) into VGPRs
  const int fbo = ((lane >> 4) * 16 + (lane & 15)) * 8;
  bf16x8 wreg[32];
#pragma unroll
  for (int kt = 0; kt < 32; kt++)
    wreg[kt] = *(const bf16x8*)(wlds + kt * 512 + fbo);

  const int b_t = tid >> 2, c_t = tid & 3;
  const int slen = seq_len[b_t];
  float c_reg = 0.f, h_reg = 0.f;

  // A-fragment base in u64 units: row*256 + (lane>>4)*2 (+ kt*8)
  const int arow = wave * 16 + (lane & 15);
  const int a64 = arow * 256 + (lane >> 4) * 2;
  const int q = lane >> 4, col = lane & 15;
  const f32x4 zero4 = {0.f, 0.f, 0.f, 0.f};

  u64* hb64 = (u64*)hbuf;                 // [2][16384] u64 double buffer
  uint32_t* phase = bar + 9 * 32;         // published step

  // xw register prefetch for t=0
  const u16* xwp0 = xw + ((size_t)gid * 64 + b_t) * 16 + c_t;
  u16 xwi = xwp0[0], xwj = xwp0[4], xwf = xwp0[8], xwo = xwp0[12];

  for (int t = 0; t < Tdim; t++) {
    const u64* h64 = hb64 + (size_t)(t & 1) * 16384;

    // h @ W_h partial: A-fragments via 8B agent-atomic loads (MALL-direct, always fresh)
    f32x4 acc[4] = {zero4, zero4, zero4, zero4};
#pragma unroll
    for (int kt = 0; kt < 32; kt++) {
      union { u64 qv[2]; bf16x8 b; } u;
      u.qv[0] = __hip_atomic_load(h64 + a64 + kt * 8,     __ATOMIC_RELAXED, __HIP_MEMORY_SCOPE_AGENT);
      u.qv[1] = __hip_atomic_load(h64 + a64 + kt * 8 + 1, __ATOMIC_RELAXED, __HIP_MEMORY_SCOPE_AGENT);
      acc[kt & 3] = mfma_bf16(u.b, wreg[kt], acc[kt & 3]);
    }

    { // z tile -> LDS
      const int r0 = wave * 16 + q * 4;
#pragma unroll
      for (int i = 0; i < 4; i++)
        zlds[(r0 + i) * 17 + col] = acc[0][i] + acc[1][i] + acc[2][i] + acc[3][i];
    }
    __syncthreads();
    { // gates + state update: thread owns (batch b_t, h-col gid*4+c_t)
      float zi = zlds[b_t * 17 + 0  + c_t] + bf2f(xwi);
      float zj = zlds[b_t * 17 + 4  + c_t] + bf2f(xwj);
      float zf = zlds[b_t * 17 + 8  + c_t] + bf2f(xwf);
      float zo = zlds[b_t * 17 + 12 + c_t] + bf2f(xwo);
      if (t < slen) {
        c_reg = c_reg * sigm(zf + 1.0f) + sigm(zi) * tanh_fast(zj);
        h_reg = tanh_fast(c_reg) * sigm(zo);
      }
      hlds[tid] = f2bf(h_reg);           // hlds[b_t*4 + c_t]
    }

    if (t < Tdim - 1) {
      // prefetch next step's xw into registers (in flight across the barrier)
      const u16* nx = xw + ((((size_t)(t + 1)) * 256 + gid) * 64 + b_t) * 16 + c_t;
      const u16 n_i = nx[0], n_j = nx[4], n_f = nx[8], n_o = nx[12];

      __syncthreads();                   // hlds complete
      if (tid < 64) {                    // wave 0: pack + 8B atomic store to MALL
        union { u16 h[4]; u64 qv; } pk;
        pk.h[0] = hlds[tid * 4 + 0];
        pk.h[1] = hlds[tid * 4 + 1];
        pk.h[2] = hlds[tid * 4 + 2];
        pk.h[3] = hlds[tid * 4 + 3];
        __hip_atomic_store(hb64 + (size_t)((t + 1) & 1) * 16384 + tid * 256 + gid,
                           pk.qv, __ATOMIC_RELAXED, __HIP_MEMORY_SCOPE_AGENT);
      }
      __syncthreads();                   // wave0's store ack'd at MALL (vmcnt0 @ barrier)

      if (tid == 0) {
        const uint32_t tgt = (uint32_t)(t + 1);
        // two-level arrive: 8 spread counters (32 WGs each) -> 1 super-counter
        const uint32_t o1 = __hip_atomic_fetch_add(&bar[(gid & 7) * 32], 1u,
                                                   __ATOMIC_RELAXED, __HIP_MEMORY_SCOPE_AGENT);
        if (o1 == tgt * 32u - 1u) {
          const uint32_t o2 = __hip_atomic_fetch_add(&bar[8 * 32], 1u,
                                                     __ATOMIC_RELAXED, __HIP_MEMORY_SCOPE_AGENT);
          if (o2 == tgt * 8u - 1u)
            __hip_atomic_store(phase, tgt, __ATOMIC_RELAXED, __HIP_MEMORY_SCOPE_AGENT);
        }
        uint32_t guard = 0;
        while (__hip_atomic_load(phase, __ATOMIC_RELAXED, __HIP_MEMORY_SCOPE_AGENT) < tgt) {
          if (++guard > 65536u) break;   // anti-wedge: fail fast, not hang
          __builtin_amdgcn_s_sleep(2);
        }
      }
      __syncthreads();                   // WG proceeds into step t+1

      xwi = n_i; xwj = n_j; xwf = n_f; xwo = n_o;
    }
  }
  out[(size_t)b_t * Hdim + gid * 4 + c_t] = h_reg;
}

// ---------- host ----------
extern "C" void kernel_launch(void* const* d_in, const int* in_sizes, int n_in,
                              void* d_out, int out_size, void* d_ws, size_t ws_size,
                              hipStream_t stream) {
  (void)in_sizes; (void)n_in; (void)out_size; (void)ws_size;
  const float* x       = (const float*)d_in[0];
  const int*   seq_len = (const int*)d_in[1];
  const float* W       = (const float*)d_in[2];
  const float* bias    = (const float*)d_in[3];
  float* out = (float*)d_out;

  char* ws = (char*)d_ws;
  u16*   xw   = (u16*)(ws);                                  // 128 MB [T][256][64][16] bf16
  u16*   xb   = (u16*)(ws + (size_t)134217728);              // 16 MB  x bf16 [B][T][D]
  u16*   wxt  = (u16*)(ws + (size_t)150994944);              // 4 MB   WxT bf16 [4096][512]
  char*  hreg = ws + (size_t)155189248;                      // 256 KB h dbuf + barrier lines
  u16*   hbuf = (u16*)hreg;
  uint32_t* bar = (uint32_t*)(hreg + 262144);                // 8 ctrs + super + phase (128B apart)

  k_init<<<dim3(129), dim3(256), 0, stream>>>((u64*)hreg);   // zero h dbuf + bar
  k_convert_x<<<dim3(8192), dim3(256), 0, stream>>>(x, xb);
  k_transpose_wx<<<dim3(8, 64), dim3(256), 0, stream>>>(W, wxt);
  k_gemm_xw<<<dim3(128, 32), dim3(256), 0, stream>>>(xb, wxt, bias, xw);

  void* args[6];
  args[0] = (void*)&W;
  args[1] = (void*)&xw;
  args[2] = (void*)&seq_len;
  args[3] = (void*)&hbuf;
  args[4] = (void*)&bar;
  args[5] = (void*)&out;
  (void)hipLaunchCooperativeKernel((const void*)k_lstm, dim3(256), dim3(256), args, 0, stream);
}